// Round 4
// baseline (1160.978 us; speedup 1.0000x reference)
//
#include <hip/hip_runtime.h>
#include <cstdint>
#include <cstddef>

typedef unsigned short u16;
typedef unsigned int u32;
typedef __attribute__((ext_vector_type(8))) short bf16x8;
typedef __attribute__((ext_vector_type(4))) float f32x4;

// ---------- bf16 helpers (raw-bit; software RNE — compiler-scheduled, known-good) ----------
__device__ __forceinline__ float bf2f(u32 u) {
  union { u32 i; float f; } c; c.i = u << 16; return c.f;
}
__device__ __forceinline__ u16 f2bf(float f) {
  union { float f; u32 i; } c; c.f = f;
  u32 r = c.i + 0x7fffu + ((c.i >> 16) & 1u);  // RNE
  return (u16)(r >> 16);
}

// exact-GELU via Abramowitz-Stegun 7.1.26 erf approx (|err| <= 1.5e-7, far below bf16 LSB).
// ~15 VALU + 2 trans vs erff's ~30+. Uses compiler builtin rcp (hazards handled by compiler).
__device__ __forceinline__ float gelu_f(float x) {
  float z = 0.70710678118654752f * x;
  float az = fabsf(z);
  float d = __builtin_fmaf(0.3275911f, az, 1.f);
  float t = __builtin_amdgcn_rcpf(d);
  float p = t * (0.254829592f + t * (-0.284496736f + t * (1.421413741f +
            t * (-1.453152027f + t * 1.061405429f))));
  float e = __expf(-az * az);
  float er = __builtin_fmaf(-p, e, 1.f);   // erf(|z|)
  er = copysignf(er, z);
  return 0.5f * x * (1.f + er);
}

// window-token row m (0..50175) -> source token row in (B,L) layout, with optional shift roll
__device__ __forceinline__ int srcrow_map(int m, int shifted) {
  int w = m / 49, n = m - w * 49;
  int b = w >> 6, wi = w & 63;
  int wy = wi >> 3, wx = wi & 7;
  int ty = n / 7, tx = n - ty * 7;
  int h = wy * 7 + ty, x = wx * 7 + tx;
  if (shifted) { h += 3; if (h >= 56) h -= 56; x += 3; if (x >= 56) x -= 56; }
  return b * 3136 + h * 56 + x;
}

// ---------------- dtype detection: are inputs packed bf16 or fp32? ----------------
__global__ void detect_kernel(const u32* __restrict__ x, int* __restrict__ flag) {
  int t = threadIdx.x;
  int c = 0;
  for (int i = t; i < 1024; i += 256) {
    u32 e = (x[i] >> 7) & 0xFFu;
    c += (e >= 100 && e <= 130) ? 1 : 0;
  }
#pragma unroll
  for (int m = 1; m < 64; m <<= 1) c += __shfl_xor(c, m, 64);
  __shared__ int part[4];
  if ((t & 63) == 0) part[t >> 6] = c;
  __syncthreads();
  if (t == 0) flag[0] = (part[0] + part[1] + part[2] + part[3] > 700) ? 1 : 0;
}

// ---------------- convert any input tensor to canonical bf16 (4 elems/thread) ----------------
__global__ void convert_kernel(const void* __restrict__ in, u16* __restrict__ out,
                               int n4, const int* __restrict__ flag) {
  int i = blockIdx.x * 256 + threadIdx.x;
  if (i >= n4) return;
  if (flag[0]) {
    ((uint2*)out)[i] = ((const uint2*)in)[i];
  } else {
    float4 v = ((const float4*)in)[i];
    uint2 r;
    r.x = (u32)f2bf(v.x) | ((u32)f2bf(v.y) << 16);
    r.y = (u32)f2bf(v.z) | ((u32)f2bf(v.w) << 16);
    ((uint2*)out)[i] = r;
  }
}

// ---------------- weight transpose (+convert): out[b][c][r] = in[b][r][c] ----------------
__global__ void transpose_kernel(const void* __restrict__ in, u16* __restrict__ out,
                                 int R, int C, int total, const int* __restrict__ flag) {
  int i = blockIdx.x * 256 + threadIdx.x;
  if (i >= total) return;
  int rc = R * C;
  int bb = i / rc, rem = i - bb * rc;
  int c = rem / R, r = rem - c * R;
  size_t s = (size_t)bb * rc + (size_t)r * C + c;
  out[i] = flag[0] ? ((const u16*)in)[s] : f2bf(((const float*)in)[s]);
}

// ---------------- LayerNorm over 384, one wave per row (bf16 in/out) ----------------
__global__ __launch_bounds__(256)
void ln384_kernel(const u16* __restrict__ in, const u16* __restrict__ g,
                  const u16* __restrict__ b, u16* __restrict__ out) {
  int row = blockIdx.x * 4 + (threadIdx.x >> 6);
  int lane = threadIdx.x & 63;
  const u32* p = (const u32*)(in + (size_t)row * 384);
  float x[6]; float sum = 0.f, sq = 0.f;
#pragma unroll
  for (int j = 0; j < 3; ++j) {
    u32 u = p[lane + 64 * j];
    float a0 = bf2f(u & 0xffff), a1 = bf2f(u >> 16);
    x[2 * j] = a0; x[2 * j + 1] = a1;
    sum += a0 + a1; sq += a0 * a0 + a1 * a1;
  }
#pragma unroll
  for (int m = 1; m < 64; m <<= 1) { sum += __shfl_xor(sum, m, 64); sq += __shfl_xor(sq, m, 64); }
  float mean = sum * (1.f / 384.f);
  float var = sq * (1.f / 384.f) - mean * mean;
  float rstd = rsqrtf(var + 1e-5f);
  u32* op = (u32*)(out + (size_t)row * 384);
  const u32* g32 = (const u32*)g; const u32* b32 = (const u32*)b;
#pragma unroll
  for (int j = 0; j < 3; ++j) {
    int c = lane + 64 * j;
    u32 gg = g32[c], bb = b32[c];
    float y0 = (x[2 * j] - mean) * rstd * bf2f(gg & 0xffff) + bf2f(bb & 0xffff);
    float y1 = (x[2 * j + 1] - mean) * rstd * bf2f(gg >> 16) + bf2f(bb >> 16);
    op[c] = (u32)f2bf(y0) | ((u32)f2bf(y1) << 16);
  }
}

// ---------------- final LN over 192 with pixel-shuffle gather; flag-typed store ----------------
__global__ __launch_bounds__(256)
void lnfinal_kernel(const u16* __restrict__ in, const u16* __restrict__ g,
                    const u16* __restrict__ b, void* __restrict__ outv,
                    const int* __restrict__ flag) {
  int row = blockIdx.x * 8 + (threadIdx.x >> 5);  // rows = 16*12544 = 200704
  int s = threadIdx.x & 31;
  int fl = flag[0];
  int bb = row / 12544, rem = row - bb * 12544;
  int hh = rem / 112, wp = rem - hh * 112;
  int h = hh >> 1, a = hh & 1, w = wp >> 1, c2 = wp & 1;
  const u32* p = (const u32*)(in + ((size_t)(bb * 3136 + h * 56 + w)) * 768 + (a * 2 + c2) * 192);
  float x[6]; float sum = 0.f, sq = 0.f;
#pragma unroll
  for (int j = 0; j < 3; ++j) {
    u32 u = p[s + 32 * j];
    float a0 = bf2f(u & 0xffff), a1 = bf2f(u >> 16);
    x[2 * j] = a0; x[2 * j + 1] = a1;
    sum += a0 + a1; sq += a0 * a0 + a1 * a1;
  }
#pragma unroll
  for (int m = 1; m < 32; m <<= 1) { sum += __shfl_xor(sum, m, 32); sq += __shfl_xor(sq, m, 32); }
  float mean = sum * (1.f / 192.f);
  float var = sq * (1.f / 192.f) - mean * mean;
  float rstd = rsqrtf(var + 1e-5f);
  const u32* g32 = (const u32*)g; const u32* b32 = (const u32*)b;
#pragma unroll
  for (int j = 0; j < 3; ++j) {
    int c = s + 32 * j;
    u32 gg = g32[c], bv = b32[c];
    float y0 = (x[2 * j] - mean) * rstd * bf2f(gg & 0xffff) + bf2f(bv & 0xffff);
    float y1 = (x[2 * j + 1] - mean) * rstd * bf2f(gg >> 16) + bf2f(bv >> 16);
    if (fl) {
      u32* op = (u32*)((u16*)outv + (size_t)row * 192);
      op[c] = (u32)f2bf(y0) | ((u32)f2bf(y1) << 16);
    } else {
      float2* op = (float2*)((float*)outv + (size_t)row * 192);
      float2 v; v.x = y0; v.y = y1;
      op[c] = v;
    }
  }
}

// ---------------- MFMA GEMM: C[M,N] = A[M,K] @ Bt[N,K]^T (+epilogue) ----------------
// 1D grid with XCD-chunked bijective swizzle (T1); double-buffered LDS 2-phase.
// Epilogue is VALU-minimized: per-(mt,r) row offsets precomputed; per-nt lane-uniform
// constants hoisted; A-S GELU.
// MODE 0: QKV   A gathered via window map; +bias; q*=1/sqrt(32); scatter [part][w][head][n][hd]
// MODE 1: PROJ  +bias +resid[src]; scatter rows via window map -> C[src] (in-place with resid)
// MODE 2: FC1   +bias; GELU; C row-major stride N
// MODE 3: FC2   +bias +resid[row]; C[row] (in-place with resid)
// MODE 4: EXPAND no bias; C row-major stride N
template <int MODE>
__global__ __launch_bounds__(256, 2)
void gemm_kernel(const u16* __restrict__ A, const u16* __restrict__ Bt,
                 const u16* __restrict__ bias, const u16* __restrict__ resid,
                 u16* __restrict__ C, int N, int K, int shifted, int nn) {
  __shared__ __attribute__((aligned(16))) char smem[32768];  // 2 x { A[128][32], B[128][32] } bf16

  const int t = threadIdx.x;
  const int lane = t & 63;
  const int wave = t >> 6;

  // T1: XCD-aware swizzle (gridDim.x % 8 == 0 for all launches -> bijective chunked map)
  const int wgid = (blockIdx.x & 7) * ((int)gridDim.x >> 3) + (blockIdx.x >> 3);
  const int mblk = wgid / nn, nblk = wgid - mblk * nn;

  // staging: 512 chunks of 16B per tile; thread t stages chunks t and t+256
  const u16* aptr[2]; const u16* bptr[2];
  char* ldsa[2]; char* ldsb[2];
#pragma unroll
  for (int i = 0; i < 2; ++i) {
    int c = t + i * 256;
    int r = c >> 2, off8 = (c & 3) * 8;
    int gr = mblk * 128 + r;
    int src = (MODE == 0) ? srcrow_map(gr, shifted) : gr;
    aptr[i] = A + (size_t)src * K + off8;
    int gn = nblk * 128 + r;
    bptr[i] = Bt + (size_t)gn * K + off8;
    ldsa[i] = smem + c * 16;
    ldsb[i] = smem + 8192 + c * 16;
  }

  f32x4 acc[4][4];
#pragma unroll
  for (int i = 0; i < 4; ++i)
#pragma unroll
    for (int j = 0; j < 4; ++j) { f32x4 z = {0.f, 0.f, 0.f, 0.f}; acc[i][j] = z; }

  const int quad = lane >> 4, l15 = lane & 15;
  const int wm = (wave >> 1) * 64, wn = (wave & 1) * 64;

  auto stage = [&](int b) {
#pragma unroll
    for (int i = 0; i < 2; ++i) {
      __builtin_amdgcn_global_load_lds((const void*)aptr[i], (void*)(ldsa[i] + b * 16384), 16, 0, 0);
      __builtin_amdgcn_global_load_lds((const void*)bptr[i], (void*)(ldsb[i] + b * 16384), 16, 0, 0);
      aptr[i] += 32; bptr[i] += 32;
    }
  };
  auto compute = [&](int b) {
    const u16* As = (const u16*)(smem + b * 16384);
    const u16* Bs = (const u16*)(smem + b * 16384 + 8192);
    bf16x8 af[4], bfv[4];
#pragma unroll
    for (int mt = 0; mt < 4; ++mt)
      af[mt] = *(const bf16x8*)(As + (wm + mt * 16 + l15) * 32 + quad * 8);
#pragma unroll
    for (int nt = 0; nt < 4; ++nt)
      bfv[nt] = *(const bf16x8*)(Bs + (wn + nt * 16 + l15) * 32 + quad * 8);
#pragma unroll
    for (int mt = 0; mt < 4; ++mt)
#pragma unroll
      for (int nt = 0; nt < 4; ++nt)
        acc[mt][nt] = __builtin_amdgcn_mfma_f32_16x16x32_bf16(af[mt], bfv[nt], acc[mt][nt], 0, 0, 0);
  };

  // 2-phase: prologue stage, then {stage(next); compute(cur); barrier}
  const int ktiles = K >> 5;
  stage(0);
  __syncthreads();
  int cur = 0;
  for (int kt = 0; kt < ktiles - 1; ++kt) {
    stage(cur ^ 1);
    compute(cur);
    __syncthreads();
    cur ^= 1;
  }
  compute(cur);

  // ---- epilogue ----
  // per-(mt,r) row constants (divisions hoisted out of the nt loop)
  size_t rowoff[4][4];
#pragma unroll
  for (int mt = 0; mt < 4; ++mt) {
#pragma unroll
    for (int r = 0; r < 4; ++r) {
      int rr = mblk * 128 + wm + mt * 16 + quad * 4 + r;
      if (MODE == 0) {
        int w49 = rr / 49, n49 = rr - w49 * 49;
        rowoff[mt][r] = (size_t)(w49 * 18816 + n49 * 32);   // w49*12*49*32 + n49*32
      } else if (MODE == 1) {
        rowoff[mt][r] = (size_t)srcrow_map(rr, shifted) * 384;
      } else {
        rowoff[mt][r] = (size_t)rr * (size_t)N;
      }
    }
  }
#pragma unroll
  for (int nt = 0; nt < 4; ++nt) {
    const int cb = nblk * 128 + wn + nt * 16;   // lane-uniform col base (mult of 16)
    const int col = cb + l15;
    const float bcol = (MODE == 4) ? 0.f : bf2f(bias[col]);
    size_t ntoff; float qsc = 1.f;
    if (MODE == 0) {
      // col-derived index pieces: part/head are lane-uniform (16-col tile never straddles
      // a 384- or 32-boundary since cb % 16 == 0)
      int part = cb / 384;
      int cw = cb - part * 384;
      int head = cw >> 5, hdb = cw & 31;
      qsc = (part == 0) ? 0.17677669529663689f : 1.f;  // HD^-0.5 on q
      ntoff = (size_t)part * 19267584 + (size_t)head * 1568 + (size_t)(hdb + l15);
    } else {
      ntoff = (size_t)col;
    }
#pragma unroll
    for (int mt = 0; mt < 4; ++mt) {
#pragma unroll
      for (int r = 0; r < 4; ++r) {
        float v = acc[mt][nt][r];
        size_t o = rowoff[mt][r] + ntoff;
        if (MODE == 0) {
          C[o] = f2bf((v + bcol) * qsc);
        } else if (MODE == 1) {
          C[o] = f2bf(v + bcol + bf2f(resid[o]));
        } else if (MODE == 2) {
          C[o] = f2bf(gelu_f(v + bcol));
        } else if (MODE == 3) {
          C[o] = f2bf(v + bcol + bf2f(resid[o]));
        } else {
          C[o] = f2bf(v);
        }
      }
    }
  }
}

// ---------------- bias+mask table precompute: bt[cls][head][i][j] f32 ----------------
// cls = (wy==7)*2 + (wx==7): window edge class. Mask (-100) folded in when shifted.
__global__ void biastab_kernel(const u16* __restrict__ rpb, float* __restrict__ bt, int shifted) {
  int idx = blockIdx.x * 256 + threadIdx.x;
  if (idx >= 4 * 12 * 2401) return;
  int ij = idx % 2401, ch = idx / 2401;
  int head = ch % 12, cls = ch / 12;
  int i = ij / 49, j = ij % 49;
  int iy = i / 7, ix = i - iy * 7, jy = j / 7, jx = j - jy * 7;
  int rp = (iy - jy + 6) * 13 + (ix - jx + 6);
  float v = bf2f(rpb[rp * 12 + head]);
  if (shifted) {
    int clsy = cls >> 1, clsx = cls & 1;
    int regi = (clsy ? (iy < 4 ? 1 : 2) : 0) * 3 + (clsx ? (ix < 4 ? 1 : 2) : 0);
    int regj = (clsy ? (jy < 4 ? 1 : 2) : 0) * 3 + (clsx ? (jx < 4 ? 1 : 2) : 0);
    if (regi != regj) v -= 100.f;
  }
  bt[idx] = v;
}

// ---------------- MFMA attention: one wave per (window, head) ----------------
// qkv layout: [part 0..2][w 0..1023][head 0..11][n 0..48][hd 0..31] bf16; N padded 49->64.
// QK^T: 16 mfma_16x16x32; softmax in-register (16-lane shfl reductions);
// P -> XOR-swizzled LDS (8KB/wave) as bf16; PV: 16 mfma with V fragments gathered to regs.
__global__ __launch_bounds__(256, 3)
void attn_mfma_kernel(const u16* __restrict__ qkv, const float* __restrict__ bt,
                      u16* __restrict__ o) {
  __shared__ __attribute__((aligned(16))) char pbuf[4][8192];
  const int wave = threadIdx.x >> 6;
  const int lane = threadIdx.x & 63;
  const int quad = lane >> 4, l15 = lane & 15;
  const int blk = blockIdx.x * 4 + wave;
  const int w = blk / 12, head = blk - w * 12;
  const int wi = w & 63;
  const int cls = (((wi >> 3) == 7) ? 2 : 0) + (((wi & 7) == 7) ? 1 : 0);
  const float* btw = bt + (size_t)(cls * 12 + head) * 2401;
  char* pw = &pbuf[wave][0];

  const size_t base = (size_t)blk * 1568;
  const u16* qp = qkv + base;
  const u16* kp = qkv + 19267584 + base;
  const u16* vp = qkv + 2 * 19267584 + base;

  // Q/K fragments: row/col = tile*16 + l15, k = quad*8 + 0..7  (16B contiguous loads)
  bf16x8 qf[4], kf[4];
#pragma unroll
  for (int mi = 0; mi < 4; ++mi)
    qf[mi] = *(const bf16x8*)(qp + (size_t)(mi * 16 + l15) * 32 + quad * 8);
#pragma unroll
  for (int nj = 0; nj < 4; ++nj)
    kf[nj] = *(const bf16x8*)(kp + (size_t)(nj * 16 + l15) * 32 + quad * 8);

  // V fragments (B-operand for PV): vf[kk][n2][j] = V[kk*32+quad*8+j][n2*16+l15]
  // keys >= 49 zeroed in-register (last block over-reads uninitialized ws -> must not enter MFMA)
  bf16x8 vf[2][2];
#pragma unroll
  for (int kk = 0; kk < 2; ++kk)
#pragma unroll
    for (int n2 = 0; n2 < 2; ++n2) {
      bf16x8 tv;
#pragma unroll
      for (int j = 0; j < 8; ++j) {
        int key = kk * 32 + quad * 8 + j;
        u16 raw = vp[(size_t)key * 32 + n2 * 16 + l15];
        tv[j] = (key < 49) ? (short)raw : (short)0;
      }
      vf[kk][n2] = tv;
    }

  // S = Q K^T  (64x64 padded)
  f32x4 s[4][4];
#pragma unroll
  for (int mi = 0; mi < 4; ++mi)
#pragma unroll
    for (int nj = 0; nj < 4; ++nj) { f32x4 z = {0.f, 0.f, 0.f, 0.f}; s[mi][nj] = z; }
#pragma unroll
  for (int mi = 0; mi < 4; ++mi)
#pragma unroll
    for (int nj = 0; nj < 4; ++nj)
      s[mi][nj] = __builtin_amdgcn_mfma_f32_16x16x32_bf16(qf[mi], kf[nj], s[mi][nj], 0, 0, 0);

  // bias + mask + softmax per row; write normalized bf16 P to swizzled LDS
  const bool c3ok = (l15 == 0);  // col 48 is the only valid col in nj=3 tile
#pragma unroll
  for (int mi = 0; mi < 4; ++mi) {
#pragma unroll
    for (int r = 0; r < 4; ++r) {
      int i = mi * 16 + quad * 4 + r;  // C-layout row
      const float* brow = btw + i * 49;
      float v0 = s[mi][0][r] + brow[l15];
      float v1 = s[mi][1][r] + brow[l15 + 16];
      float v2 = s[mi][2][r] + brow[l15 + 32];
      float v3 = c3ok ? (s[mi][3][r] + brow[48]) : -1e30f;  // replace (kills NaN), not add
      float mx = fmaxf(fmaxf(v0, v1), fmaxf(v2, v3));
#pragma unroll
      for (int t = 1; t < 16; t <<= 1) mx = fmaxf(mx, __shfl_xor(mx, t, 64));
      float e0 = __expf(v0 - mx), e1 = __expf(v1 - mx);
      float e2 = __expf(v2 - mx), e3 = __expf(v3 - mx);
      float ls = e0 + e1 + e2 + e3;
#pragma unroll
      for (int t = 1; t < 16; t <<= 1) ls += __shfl_xor(ls, t, 64);
      float inv = 1.f / ls;
      u32 sw = (u32)((i & 7) << 4);  // G4 XOR swizzle: row stride 128B would be 32-way conflict
      *(u16*)(pw + (((u32)(i * 128 + l15 * 2)) ^ sw)) = f2bf(e0 * inv);
      *(u16*)(pw + (((u32)(i * 128 + (l15 + 16) * 2)) ^ sw)) = f2bf(e1 * inv);
      *(u16*)(pw + (((u32)(i * 128 + (l15 + 32) * 2)) ^ sw)) = f2bf(e2 * inv);
      *(u16*)(pw + (((u32)(i * 128 + (l15 + 48) * 2)) ^ sw)) = f2bf(e3 * inv);
    }
  }

  // drain P writes before A-fragment reads (same wave, private LDS region)
  asm volatile("s_waitcnt lgkmcnt(0)" ::: "memory");
  __builtin_amdgcn_sched_barrier(0);

  // O = P V
  f32x4 oacc[4][2];
#pragma unroll
  for (int mi = 0; mi < 4; ++mi)
#pragma unroll
    for (int n2 = 0; n2 < 2; ++n2) { f32x4 z = {0.f, 0.f, 0.f, 0.f}; oacc[mi][n2] = z; }
#pragma unroll
  for (int mi = 0; mi < 4; ++mi) {
#pragma unroll
    for (int kk = 0; kk < 2; ++kk) {
      int arow = mi * 16 + l15;
      u32 ab = ((u32)(arow * 128 + (kk * 32 + quad * 8) * 2)) ^ ((u32)((arow & 7) << 4));
      bf16x8 pf = *(const bf16x8*)(pw + ab);
#pragma unroll
      for (int n2 = 0; n2 < 2; ++n2)
        oacc[mi][n2] = __builtin_amdgcn_mfma_f32_16x16x32_bf16(pf, vf[kk][n2], oacc[mi][n2], 0, 0, 0);
    }
  }

  // store valid rows (row < 49): o[(w*49+row)*384 + head*32 + hd]
#pragma unroll
  for (int mi = 0; mi < 4; ++mi)
#pragma unroll
    for (int r = 0; r < 4; ++r) {
      int row = mi * 16 + quad * 4 + r;
      if (row < 49) {
        u16* orow = o + ((size_t)(w * 49 + row)) * 384 + head * 32;
        orow[l15] = f2bf(oacc[mi][0][r]);
        orow[16 + l15] = f2bf(oacc[mi][1][r]);
      }
    }
}

// ---------------- host orchestration ----------------
extern "C" void kernel_launch(void* const* d_in, const int* in_sizes, int n_in,
                              void* d_out, int out_size, void* d_ws, size_t ws_size,
                              hipStream_t stream) {
  char* ws = (char*)d_ws;
  u16* wsA  = (u16*)ws;                          // 154,140,672 B: QKV / FC1-act / expand-out
  u16* wsS  = (u16*)(ws + 154140672);            // 38,535,168 B: converted x -> residual stream (in-place)
  u16* wsB  = (u16*)(ws + 192675840);            // 38,535,168 B: LN out / attn out
  u16* wsT  = (u16*)(ws + 231211008);            // 7,667,712 B: transposed weights
  u16* wsP  = (u16*)(ws + 238878720);            // 28,848 B: converted params
  int* flag = (int*)(ws + 238907568);            // 4 B
  // bias table parked in wsA tail: QKV occupies first 115,605,504 B (+ <1KB over-read slack);
  // FC1 later overwrites it, so it is rebuilt every block-iteration before attention.
  float* bt = (float*)(ws + 115736576);          // 4*12*2401 f32 (+ gather slack)

  u16* qkvT  = wsT;                  // [2][1152][384]
  u16* projT = qkvT + 2 * 442368;    // [2][384][384]
  u16* fc1T  = projT + 2 * 147456;   // [2][1536][384]
  u16* fc2T  = fc1T + 2 * 589824;    // [2][384][1536]
  u16* expT  = fc2T + 2 * 589824;    // [768][384]

  u16* p_n1g  = wsP + 0;      // 768
  u16* p_n1b  = wsP + 768;    // 768
  u16* p_qkvb = wsP + 1536;   // 2304
  u16* p_rpb  = wsP + 3840;   // 4056
  u16* p_prjb = wsP + 7896;   // 768
  u16* p_n2g  = wsP + 8664;   // 768
  u16* p_n2b  = wsP + 9432;   // 768
  u16* p_fc1b = wsP + 10200;  // 3072
  u16* p_fc2b = wsP + 13272;  // 768
  u16* p_exg  = wsP + 14040;  // 192
  u16* p_exb  = wsP + 14232;  // 192

  // 1) dtype detection from x's bit patterns
  detect_kernel<<<1, 256, 0, stream>>>((const u32*)d_in[0], flag);

  // 2) convert x and small params to canonical bf16 (vectorized x4)
  convert_kernel<<<(19267584 / 4 + 255) / 256, 256, 0, stream>>>(d_in[0], wsS, 19267584 / 4, flag);
  auto cv = [&](const void* src, u16* dst, int n) {
    convert_kernel<<<(n / 4 + 255) / 256, 256, 0, stream>>>(src, dst, n / 4, flag);
  };
  cv(d_in[1],  p_n1g, 768);   cv(d_in[2],  p_n1b, 768);
  cv(d_in[4],  p_qkvb, 2304); cv(d_in[5],  p_rpb, 4056);
  cv(d_in[7],  p_prjb, 768);  cv(d_in[8],  p_n2g, 768);
  cv(d_in[9],  p_n2b, 768);   cv(d_in[11], p_fc1b, 3072);
  cv(d_in[13], p_fc2b, 768);  cv(d_in[15], p_exg, 192);
  cv(d_in[16], p_exb, 192);

  // 3) weight transposes (+convert)
  {
    int tot;
    tot = 2 * 384 * 1152; transpose_kernel<<<(tot + 255) / 256, 256, 0, stream>>>(d_in[3],  qkvT, 384, 1152, tot, flag);
    tot = 2 * 384 * 384;  transpose_kernel<<<(tot + 255) / 256, 256, 0, stream>>>(d_in[6],  projT, 384, 384,  tot, flag);
    tot = 2 * 384 * 1536; transpose_kernel<<<(tot + 255) / 256, 256, 0, stream>>>(d_in[10], fc1T, 384, 1536, tot, flag);
    tot = 2 * 1536 * 384; transpose_kernel<<<(tot + 255) / 256, 256, 0, stream>>>(d_in[12], fc2T, 1536, 384, tot, flag);
    tot = 384 * 768;      transpose_kernel<<<(tot + 255) / 256, 256, 0, stream>>>(d_in[14], expT, 384, 768,  tot, flag);
  }

  // 4) two Swin blocks; residual stream lives in wsS (in-place updates)
  for (int i = 0; i < 2; ++i) {
    int shifted = i;
    // bias+mask table for this block (depends on rpb[i] and shifted)
    biastab_kernel<<<451, 256, 0, stream>>>(p_rpb + i * 2028, bt, shifted);
    // LN1 -> wsB
    ln384_kernel<<<12544, 256, 0, stream>>>(wsS, p_n1g + i * 384, p_n1b + i * 384, wsB);
    // QKV gemm (gathered windows) -> wsA (q/k/v scattered per head); grid 392*9 = 3528
    gemm_kernel<0><<<3528, 256, 0, stream>>>(wsB, qkvT + i * 442368, p_qkvb + i * 1152,
                                             nullptr, wsA, 1152, 384, shifted, 9);
    // attention (MFMA) -> wsB  ([w*49+n][head*32+hd])
    attn_mfma_kernel<<<3072, 256, 0, stream>>>(wsA, bt, wsB);
    // proj + residual + window-reverse scatter -> wsS (in-place); grid 392*3 = 1176
    gemm_kernel<1><<<1176, 256, 0, stream>>>(wsB, projT + i * 147456, p_prjb + i * 384,
                                             wsS, wsS, 384, 384, shifted, 3);
    // LN2 -> wsB
    ln384_kernel<<<12544, 256, 0, stream>>>(wsS, p_n2g + i * 384, p_n2b + i * 384, wsB);
    // FC1 + gelu -> wsA; grid 392*12 = 4704
    gemm_kernel<2><<<4704, 256, 0, stream>>>(wsB, fc1T + i * 589824, p_fc1b + i * 1536,
                                             nullptr, wsA, 1536, 384, 0, 12);
    // FC2 + residual -> wsS (in-place); grid 392*3 = 1176
    gemm_kernel<3><<<1176, 256, 0, stream>>>(wsA, fc2T + i * 589824, p_fc2b + i * 384,
                                             wsS, wsS, 384, 1536, 0, 3);
  }

  // 5) PatchExpand gemm -> wsA [50176][768]; grid 392*6 = 2352
  gemm_kernel<4><<<2352, 256, 0, stream>>>(wsS, expT, nullptr, nullptr, wsA, 768, 384, 0, 6);
  // 6) pixel-shuffle gather + LN(192) -> d_out (bf16 or fp32 per flag)
  lnfinal_kernel<<<25088, 256, 0, stream>>>(wsA, p_exg, p_exb, d_out, flag);
}

// Round 5
// 1077.620 us; speedup vs baseline: 1.0774x; 1.0774x over previous
//
#include <hip/hip_runtime.h>
#include <cstdint>
#include <cstddef>

typedef unsigned short u16;
typedef unsigned int u32;
typedef __attribute__((ext_vector_type(8))) short bf16x8;
typedef __attribute__((ext_vector_type(4))) float f32x4;

// ---------- bf16 helpers (raw-bit; software RNE — compiler-scheduled, known-good) ----------
__device__ __forceinline__ float bf2f(u32 u) {
  union { u32 i; float f; } c; c.i = u << 16; return c.f;
}
__device__ __forceinline__ u16 f2bf(float f) {
  union { float f; u32 i; } c; c.f = f;
  u32 r = c.i + 0x7fffu + ((c.i >> 16) & 1u);  // RNE
  return (u16)(r >> 16);
}

// exact-GELU via Abramowitz-Stegun 7.1.26 erf approx (|err| <= 1.5e-7, far below bf16 LSB).
__device__ __forceinline__ float gelu_f(float x) {
  float z = 0.70710678118654752f * x;
  float az = fabsf(z);
  float d = __builtin_fmaf(0.3275911f, az, 1.f);
  float t = __builtin_amdgcn_rcpf(d);
  float p = t * (0.254829592f + t * (-0.284496736f + t * (1.421413741f +
            t * (-1.453152027f + t * 1.061405429f))));
  float e = __expf(-az * az);
  float er = __builtin_fmaf(-p, e, 1.f);   // erf(|z|)
  er = copysignf(er, z);
  return 0.5f * x * (1.f + er);
}

// window-token row m (0..50175) -> source token row in (B,L) layout, with optional shift roll
__device__ __forceinline__ int srcrow_map(int m, int shifted) {
  int w = m / 49, n = m - w * 49;
  int b = w >> 6, wi = w & 63;
  int wy = wi >> 3, wx = wi & 7;
  int ty = n / 7, tx = n - ty * 7;
  int h = wy * 7 + ty, x = wx * 7 + tx;
  if (shifted) { h += 3; if (h >= 56) h -= 56; x += 3; if (x >= 56) x -= 56; }
  return b * 3136 + h * 56 + x;
}

// ---------------- dtype detection: are inputs packed bf16 or fp32? ----------------
__global__ void detect_kernel(const u32* __restrict__ x, int* __restrict__ flag) {
  int t = threadIdx.x;
  int c = 0;
  for (int i = t; i < 1024; i += 256) {
    u32 e = (x[i] >> 7) & 0xFFu;
    c += (e >= 100 && e <= 130) ? 1 : 0;
  }
#pragma unroll
  for (int m = 1; m < 64; m <<= 1) c += __shfl_xor(c, m, 64);
  __shared__ int part[4];
  if ((t & 63) == 0) part[t >> 6] = c;
  __syncthreads();
  if (t == 0) flag[0] = (part[0] + part[1] + part[2] + part[3] > 700) ? 1 : 0;
}

// ---------------- convert any input tensor to canonical bf16 (4 elems/thread) ----------------
__global__ void convert_kernel(const void* __restrict__ in, u16* __restrict__ out,
                               int n4, const int* __restrict__ flag) {
  int i = blockIdx.x * 256 + threadIdx.x;
  if (i >= n4) return;
  if (flag[0]) {
    ((uint2*)out)[i] = ((const uint2*)in)[i];
  } else {
    float4 v = ((const float4*)in)[i];
    uint2 r;
    r.x = (u32)f2bf(v.x) | ((u32)f2bf(v.y) << 16);
    r.y = (u32)f2bf(v.z) | ((u32)f2bf(v.w) << 16);
    ((uint2*)out)[i] = r;
  }
}

// ---------------- weight transpose (+convert): out[b][c][r] = in[b][r][c] ----------------
__global__ void transpose_kernel(const void* __restrict__ in, u16* __restrict__ out,
                                 int R, int C, int total, const int* __restrict__ flag) {
  int i = blockIdx.x * 256 + threadIdx.x;
  if (i >= total) return;
  int rc = R * C;
  int bb = i / rc, rem = i - bb * rc;
  int c = rem / R, r = rem - c * R;
  size_t s = (size_t)bb * rc + (size_t)r * C + c;
  out[i] = flag[0] ? ((const u16*)in)[s] : f2bf(((const float*)in)[s]);
}

// ---------------- LayerNorm over 384, one wave per row (bf16 in/out) ----------------
__global__ __launch_bounds__(256)
void ln384_kernel(const u16* __restrict__ in, const u16* __restrict__ g,
                  const u16* __restrict__ b, u16* __restrict__ out) {
  int row = blockIdx.x * 4 + (threadIdx.x >> 6);
  int lane = threadIdx.x & 63;
  const u32* p = (const u32*)(in + (size_t)row * 384);
  float x[6]; float sum = 0.f, sq = 0.f;
#pragma unroll
  for (int j = 0; j < 3; ++j) {
    u32 u = p[lane + 64 * j];
    float a0 = bf2f(u & 0xffff), a1 = bf2f(u >> 16);
    x[2 * j] = a0; x[2 * j + 1] = a1;
    sum += a0 + a1; sq += a0 * a0 + a1 * a1;
  }
#pragma unroll
  for (int m = 1; m < 64; m <<= 1) { sum += __shfl_xor(sum, m, 64); sq += __shfl_xor(sq, m, 64); }
  float mean = sum * (1.f / 384.f);
  float var = sq * (1.f / 384.f) - mean * mean;
  float rstd = rsqrtf(var + 1e-5f);
  u32* op = (u32*)(out + (size_t)row * 384);
  const u32* g32 = (const u32*)g; const u32* b32 = (const u32*)b;
#pragma unroll
  for (int j = 0; j < 3; ++j) {
    int c = lane + 64 * j;
    u32 gg = g32[c], bb = b32[c];
    float y0 = (x[2 * j] - mean) * rstd * bf2f(gg & 0xffff) + bf2f(bb & 0xffff);
    float y1 = (x[2 * j + 1] - mean) * rstd * bf2f(gg >> 16) + bf2f(bb >> 16);
    op[c] = (u32)f2bf(y0) | ((u32)f2bf(y1) << 16);
  }
}

// ---------------- final LN over 192 with pixel-shuffle gather; flag-typed store ----------------
__global__ __launch_bounds__(256)
void lnfinal_kernel(const u16* __restrict__ in, const u16* __restrict__ g,
                    const u16* __restrict__ b, void* __restrict__ outv,
                    const int* __restrict__ flag) {
  int row = blockIdx.x * 8 + (threadIdx.x >> 5);  // rows = 16*12544 = 200704
  int s = threadIdx.x & 31;
  int fl = flag[0];
  int bb = row / 12544, rem = row - bb * 12544;
  int hh = rem / 112, wp = rem - hh * 112;
  int h = hh >> 1, a = hh & 1, w = wp >> 1, c2 = wp & 1;
  const u32* p = (const u32*)(in + ((size_t)(bb * 3136 + h * 56 + w)) * 768 + (a * 2 + c2) * 192);
  float x[6]; float sum = 0.f, sq = 0.f;
#pragma unroll
  for (int j = 0; j < 3; ++j) {
    u32 u = p[s + 32 * j];
    float a0 = bf2f(u & 0xffff), a1 = bf2f(u >> 16);
    x[2 * j] = a0; x[2 * j + 1] = a1;
    sum += a0 + a1; sq += a0 * a0 + a1 * a1;
  }
#pragma unroll
  for (int m = 1; m < 32; m <<= 1) { sum += __shfl_xor(sum, m, 32); sq += __shfl_xor(sq, m, 32); }
  float mean = sum * (1.f / 192.f);
  float var = sq * (1.f / 192.f) - mean * mean;
  float rstd = rsqrtf(var + 1e-5f);
  const u32* g32 = (const u32*)g; const u32* b32 = (const u32*)b;
#pragma unroll
  for (int j = 0; j < 3; ++j) {
    int c = s + 32 * j;
    u32 gg = g32[c], bv = b32[c];
    float y0 = (x[2 * j] - mean) * rstd * bf2f(gg & 0xffff) + bf2f(bv & 0xffff);
    float y1 = (x[2 * j + 1] - mean) * rstd * bf2f(gg >> 16) + bf2f(bv >> 16);
    if (fl) {
      u32* op = (u32*)((u16*)outv + (size_t)row * 192);
      op[c] = (u32)f2bf(y0) | ((u32)f2bf(y1) << 16);
    } else {
      float2* op = (float2*)((float*)outv + (size_t)row * 192);
      float2 v; v.x = y0; v.y = y1;
      op[c] = v;
    }
  }
}

// ---------------- MFMA GEMM: C[M,N] = A[M,K] @ Bt[N,K]^T (+epilogue) ----------------
// T1 XCD-chunked swizzle; T4 counted-vmcnt 3-deep LDS ring (tile k+2 in flight across
// the barrier; only tile k+1 drained -> 2x latency window vs drain-0 2-phase).
// Epilogue: row-major store order (write-coalescing; R4's nt-outer order cost +57% HBM
// writes), hoisted rowoff / per-nt tables, A-S GELU.
// MODE 0: QKV   A gathered via window map; +bias; q*=1/sqrt(32); scatter [part][w][head][n][hd]
// MODE 1: PROJ  +bias +resid[src]; scatter rows via window map -> C[src] (in-place with resid)
// MODE 2: FC1   +bias; GELU; C row-major stride N
// MODE 3: FC2   +bias +resid[row]; C[row] (in-place with resid)
// MODE 4: EXPAND no bias; C row-major stride N
template <int MODE>
__global__ __launch_bounds__(256, 2)
void gemm_kernel(const u16* __restrict__ A, const u16* __restrict__ Bt,
                 const u16* __restrict__ bias, const u16* __restrict__ resid,
                 u16* __restrict__ C, int N, int K, int shifted, int nn) {
  __shared__ __attribute__((aligned(16))) char smem[49152];  // 3 x { A[128][32], B[128][32] } bf16

  const int t = threadIdx.x;
  const int lane = t & 63;
  const int wave = t >> 6;

  // T1: XCD-aware swizzle (gridDim.x % 8 == 0 for all launches -> bijective chunked map)
  const int wgid = (blockIdx.x & 7) * ((int)gridDim.x >> 3) + (blockIdx.x >> 3);
  const int mblk = wgid / nn, nblk = wgid - mblk * nn;

  // staging: 512 chunks of 16B per tile; thread t stages chunks t and t+256 (4 loads/thread)
  const u16* aptr[2]; const u16* bptr[2];
  char* ldsa[2]; char* ldsb[2];
#pragma unroll
  for (int i = 0; i < 2; ++i) {
    int c = t + i * 256;
    int r = c >> 2, off8 = (c & 3) * 8;
    int gr = mblk * 128 + r;
    int src = (MODE == 0) ? srcrow_map(gr, shifted) : gr;
    aptr[i] = A + (size_t)src * K + off8;
    int gn = nblk * 128 + r;
    bptr[i] = Bt + (size_t)gn * K + off8;
    ldsa[i] = smem + c * 16;
    ldsb[i] = smem + 8192 + c * 16;
  }

  f32x4 acc[4][4];
#pragma unroll
  for (int i = 0; i < 4; ++i)
#pragma unroll
    for (int j = 0; j < 4; ++j) { f32x4 z = {0.f, 0.f, 0.f, 0.f}; acc[i][j] = z; }

  const int quad = lane >> 4, l15 = lane & 15;
  const int wm = (wave >> 1) * 64, wn = (wave & 1) * 64;

  auto stage = [&](int b) {
#pragma unroll
    for (int i = 0; i < 2; ++i) {
      __builtin_amdgcn_global_load_lds((const void*)aptr[i], (void*)(ldsa[i] + b * 16384), 16, 0, 0);
      __builtin_amdgcn_global_load_lds((const void*)bptr[i], (void*)(ldsb[i] + b * 16384), 16, 0, 0);
      aptr[i] += 32; bptr[i] += 32;
    }
  };
  auto compute = [&](int b) {
    const u16* As = (const u16*)(smem + b * 16384);
    const u16* Bs = (const u16*)(smem + b * 16384 + 8192);
    bf16x8 af[4], bfv[4];
#pragma unroll
    for (int mt = 0; mt < 4; ++mt)
      af[mt] = *(const bf16x8*)(As + (wm + mt * 16 + l15) * 32 + quad * 8);
#pragma unroll
    for (int nt = 0; nt < 4; ++nt)
      bfv[nt] = *(const bf16x8*)(Bs + (wn + nt * 16 + l15) * 32 + quad * 8);
#pragma unroll
    for (int mt = 0; mt < 4; ++mt)
#pragma unroll
      for (int nt = 0; nt < 4; ++nt)
        acc[mt][nt] = __builtin_amdgcn_mfma_f32_16x16x32_bf16(af[mt], bfv[nt], acc[mt][nt], 0, 0, 0);
  };

  // 3-deep ring: tiles 0,1 staged; per iter {stage k+2; compute k; vmcnt(4); barrier}.
  // vmcnt(4): each wave has 4 loads/tile in flight; waiting to 4 drains tile k+1,
  // leaves tile k+2 in flight across the barrier (T4 counted-vmcnt).
  // LDS-read safety for the raw barrier: all ds_read results are consumed by MFMAs
  // behind compiler-inserted lgkmcnt waits, so data is in VGPRs before any wave can
  // reach the barrier; buffer k%3 is only overwritten one full barrier epoch later.
  const int ktiles = K >> 5;
  stage(0);
  stage(1);
  asm volatile("s_waitcnt vmcnt(4)" ::: "memory");
  __builtin_amdgcn_s_barrier();
  __builtin_amdgcn_sched_barrier(0);
  int bcur = 0, bstage = 2;
  for (int kt = 0; kt < ktiles; ++kt) {
    const bool more2 = (kt + 2 < ktiles);
    if (more2) stage(bstage);
    compute(bcur);
    if (more2) {
      asm volatile("s_waitcnt vmcnt(4)" ::: "memory");
      __builtin_amdgcn_s_barrier();
      __builtin_amdgcn_sched_barrier(0);
    } else if (kt + 1 < ktiles) {
      asm volatile("s_waitcnt vmcnt(0)" ::: "memory");
      __builtin_amdgcn_s_barrier();
      __builtin_amdgcn_sched_barrier(0);
    }
    bcur = (bcur == 2) ? 0 : bcur + 1;
    bstage = (bstage == 2) ? 0 : bstage + 1;
  }

  // ---- epilogue ----
  // per-(mt,r) row offsets (divisions hoisted)
  size_t rowoff[4][4];
#pragma unroll
  for (int mt = 0; mt < 4; ++mt) {
#pragma unroll
    for (int r = 0; r < 4; ++r) {
      int rr = mblk * 128 + wm + mt * 16 + quad * 4 + r;
      if (MODE == 0) {
        int w49 = rr / 49, n49 = rr - w49 * 49;
        rowoff[mt][r] = (size_t)(w49 * 18816 + n49 * 32);   // w49*12*49*32 + n49*32
      } else if (MODE == 1) {
        rowoff[mt][r] = (size_t)srcrow_map(rr, shifted) * 384;
      } else {
        rowoff[mt][r] = (size_t)rr * (size_t)N;
      }
    }
  }
  // per-nt column constants
  size_t ntoff[4]; float bcolv[4]; float qscv[4];
#pragma unroll
  for (int nt = 0; nt < 4; ++nt) {
    const int cb = nblk * 128 + wn + nt * 16;   // lane-uniform col base (mult of 16)
    const int col = cb + l15;
    bcolv[nt] = (MODE == 4) ? 0.f : bf2f(bias[col]);
    qscv[nt] = 1.f;
    if (MODE == 0) {
      int part = cb / 384;
      int cw = cb - part * 384;
      int head = cw >> 5, hdb = cw & 31;
      qscv[nt] = (part == 0) ? 0.17677669529663689f : 1.f;  // HD^-0.5 on q
      ntoff[nt] = (size_t)part * 19267584 + (size_t)head * 1568 + (size_t)(hdb + l15);
    } else {
      ntoff[nt] = (size_t)col;
    }
  }
  // row-major store order: for a fixed output row, the wave's 4 nt chunks are written
  // back-to-back -> full-line HBM writes (R2-measured ideal WRITE_SIZE)
#pragma unroll
  for (int mt = 0; mt < 4; ++mt) {
#pragma unroll
    for (int r = 0; r < 4; ++r) {
      const size_t ro = rowoff[mt][r];
#pragma unroll
      for (int nt = 0; nt < 4; ++nt) {
        float v = acc[mt][nt][r];
        size_t o = ro + ntoff[nt];
        if (MODE == 0) {
          C[o] = f2bf((v + bcolv[nt]) * qscv[nt]);
        } else if (MODE == 1) {
          C[o] = f2bf(v + bcolv[nt] + bf2f(resid[o]));
        } else if (MODE == 2) {
          C[o] = f2bf(gelu_f(v + bcolv[nt]));
        } else if (MODE == 3) {
          C[o] = f2bf(v + bcolv[nt] + bf2f(resid[o]));
        } else {
          C[o] = f2bf(v);
        }
      }
    }
  }
}

// ---------------- bias+mask table precompute: bt[cls][head][i][j] f32 ----------------
// cls = (wy==7)*2 + (wx==7): window edge class. Mask (-100) folded in when shifted.
__global__ void biastab_kernel(const u16* __restrict__ rpb, float* __restrict__ bt, int shifted) {
  int idx = blockIdx.x * 256 + threadIdx.x;
  if (idx >= 4 * 12 * 2401) return;
  int ij = idx % 2401, ch = idx / 2401;
  int head = ch % 12, cls = ch / 12;
  int i = ij / 49, j = ij % 49;
  int iy = i / 7, ix = i - iy * 7, jy = j / 7, jx = j - jy * 7;
  int rp = (iy - jy + 6) * 13 + (ix - jx + 6);
  float v = bf2f(rpb[rp * 12 + head]);
  if (shifted) {
    int clsy = cls >> 1, clsx = cls & 1;
    int regi = (clsy ? (iy < 4 ? 1 : 2) : 0) * 3 + (clsx ? (ix < 4 ? 1 : 2) : 0);
    int regj = (clsy ? (jy < 4 ? 1 : 2) : 0) * 3 + (clsx ? (jx < 4 ? 1 : 2) : 0);
    if (regi != regj) v -= 100.f;
  }
  bt[idx] = v;
}

// ---------------- MFMA attention: one wave per (window, head) ----------------
// qkv layout: [part 0..2][w 0..1023][head 0..11][n 0..48][hd 0..31] bf16; N padded 49->64.
// QK^T: 16 mfma_16x16x32; softmax in-register (16-lane shfl reductions);
// P -> XOR-swizzled LDS (8KB/wave) as bf16; PV: 16 mfma with V fragments gathered to regs.
__global__ __launch_bounds__(256, 3)
void attn_mfma_kernel(const u16* __restrict__ qkv, const float* __restrict__ bt,
                      u16* __restrict__ o) {
  __shared__ __attribute__((aligned(16))) char pbuf[4][8192];
  const int wave = threadIdx.x >> 6;
  const int lane = threadIdx.x & 63;
  const int quad = lane >> 4, l15 = lane & 15;
  const int blk = blockIdx.x * 4 + wave;
  const int w = blk / 12, head = blk - w * 12;
  const int wi = w & 63;
  const int cls = (((wi >> 3) == 7) ? 2 : 0) + (((wi & 7) == 7) ? 1 : 0);
  const float* btw = bt + (size_t)(cls * 12 + head) * 2401;
  char* pw = &pbuf[wave][0];

  const size_t base = (size_t)blk * 1568;
  const u16* qp = qkv + base;
  const u16* kp = qkv + 19267584 + base;
  const u16* vp = qkv + 2 * 19267584 + base;

  // Q/K fragments: row/col = tile*16 + l15, k = quad*8 + 0..7  (16B contiguous loads)
  bf16x8 qf[4], kf[4];
#pragma unroll
  for (int mi = 0; mi < 4; ++mi)
    qf[mi] = *(const bf16x8*)(qp + (size_t)(mi * 16 + l15) * 32 + quad * 8);
#pragma unroll
  for (int nj = 0; nj < 4; ++nj)
    kf[nj] = *(const bf16x8*)(kp + (size_t)(nj * 16 + l15) * 32 + quad * 8);

  // V fragments (B-operand for PV): vf[kk][n2][j] = V[kk*32+quad*8+j][n2*16+l15]
  // keys >= 49 zeroed in-register (last block over-reads uninitialized ws -> must not enter MFMA)
  bf16x8 vf[2][2];
#pragma unroll
  for (int kk = 0; kk < 2; ++kk)
#pragma unroll
    for (int n2 = 0; n2 < 2; ++n2) {
      bf16x8 tv;
#pragma unroll
      for (int j = 0; j < 8; ++j) {
        int key = kk * 32 + quad * 8 + j;
        u16 raw = vp[(size_t)key * 32 + n2 * 16 + l15];
        tv[j] = (key < 49) ? (short)raw : (short)0;
      }
      vf[kk][n2] = tv;
    }

  // S = Q K^T  (64x64 padded)
  f32x4 s[4][4];
#pragma unroll
  for (int mi = 0; mi < 4; ++mi)
#pragma unroll
    for (int nj = 0; nj < 4; ++nj) { f32x4 z = {0.f, 0.f, 0.f, 0.f}; s[mi][nj] = z; }
#pragma unroll
  for (int mi = 0; mi < 4; ++mi)
#pragma unroll
    for (int nj = 0; nj < 4; ++nj)
      s[mi][nj] = __builtin_amdgcn_mfma_f32_16x16x32_bf16(qf[mi], kf[nj], s[mi][nj], 0, 0, 0);

  // bias + mask + softmax per row; write normalized bf16 P to swizzled LDS
  const bool c3ok = (l15 == 0);  // col 48 is the only valid col in nj=3 tile
#pragma unroll
  for (int mi = 0; mi < 4; ++mi) {
#pragma unroll
    for (int r = 0; r < 4; ++r) {
      int i = mi * 16 + quad * 4 + r;  // C-layout row
      const float* brow = btw + i * 49;
      float v0 = s[mi][0][r] + brow[l15];
      float v1 = s[mi][1][r] + brow[l15 + 16];
      float v2 = s[mi][2][r] + brow[l15 + 32];
      float v3 = c3ok ? (s[mi][3][r] + brow[48]) : -1e30f;  // replace (kills NaN), not add
      float mx = fmaxf(fmaxf(v0, v1), fmaxf(v2, v3));
#pragma unroll
      for (int t = 1; t < 16; t <<= 1) mx = fmaxf(mx, __shfl_xor(mx, t, 64));
      float e0 = __expf(v0 - mx), e1 = __expf(v1 - mx);
      float e2 = __expf(v2 - mx), e3 = __expf(v3 - mx);
      float ls = e0 + e1 + e2 + e3;
#pragma unroll
      for (int t = 1; t < 16; t <<= 1) ls += __shfl_xor(ls, t, 64);
      float inv = 1.f / ls;
      u32 sw = (u32)((i & 7) << 4);  // G4 XOR swizzle: row stride 128B would be 32-way conflict
      *(u16*)(pw + (((u32)(i * 128 + l15 * 2)) ^ sw)) = f2bf(e0 * inv);
      *(u16*)(pw + (((u32)(i * 128 + (l15 + 16) * 2)) ^ sw)) = f2bf(e1 * inv);
      *(u16*)(pw + (((u32)(i * 128 + (l15 + 32) * 2)) ^ sw)) = f2bf(e2 * inv);
      *(u16*)(pw + (((u32)(i * 128 + (l15 + 48) * 2)) ^ sw)) = f2bf(e3 * inv);
    }
  }

  // drain P writes before A-fragment reads (same wave, private LDS region)
  asm volatile("s_waitcnt lgkmcnt(0)" ::: "memory");
  __builtin_amdgcn_sched_barrier(0);

  // O = P V
  f32x4 oacc[4][2];
#pragma unroll
  for (int mi = 0; mi < 4; ++mi)
#pragma unroll
    for (int n2 = 0; n2 < 2; ++n2) { f32x4 z = {0.f, 0.f, 0.f, 0.f}; oacc[mi][n2] = z; }
#pragma unroll
  for (int mi = 0; mi < 4; ++mi) {
#pragma unroll
    for (int kk = 0; kk < 2; ++kk) {
      int arow = mi * 16 + l15;
      u32 ab = ((u32)(arow * 128 + (kk * 32 + quad * 8) * 2)) ^ ((u32)((arow & 7) << 4));
      bf16x8 pf = *(const bf16x8*)(pw + ab);
#pragma unroll
      for (int n2 = 0; n2 < 2; ++n2)
        oacc[mi][n2] = __builtin_amdgcn_mfma_f32_16x16x32_bf16(pf, vf[kk][n2], oacc[mi][n2], 0, 0, 0);
    }
  }

  // store valid rows (row < 49): o[(w*49+row)*384 + head*32 + hd]
#pragma unroll
  for (int mi = 0; mi < 4; ++mi)
#pragma unroll
    for (int r = 0; r < 4; ++r) {
      int row = mi * 16 + quad * 4 + r;
      if (row < 49) {
        u16* orow = o + ((size_t)(w * 49 + row)) * 384 + head * 32;
        orow[l15] = f2bf(oacc[mi][0][r]);
        orow[16 + l15] = f2bf(oacc[mi][1][r]);
      }
    }
}

// ---------------- host orchestration ----------------
extern "C" void kernel_launch(void* const* d_in, const int* in_sizes, int n_in,
                              void* d_out, int out_size, void* d_ws, size_t ws_size,
                              hipStream_t stream) {
  char* ws = (char*)d_ws;
  u16* wsA  = (u16*)ws;                          // 154,140,672 B: QKV / FC1-act / expand-out
  u16* wsS  = (u16*)(ws + 154140672);            // 38,535,168 B: converted x -> residual stream (in-place)
  u16* wsB  = (u16*)(ws + 192675840);            // 38,535,168 B: LN out / attn out
  u16* wsT  = (u16*)(ws + 231211008);            // 7,667,712 B: transposed weights
  u16* wsP  = (u16*)(ws + 238878720);            // 28,848 B: converted params
  int* flag = (int*)(ws + 238907568);            // 4 B
  // bias table parked in wsA tail: QKV occupies first 115,605,504 B (+ <1KB over-read slack);
  // FC1 later overwrites it, so it is rebuilt every block-iteration before attention.
  float* bt = (float*)(ws + 115736576);          // 4*12*2401 f32 (+ gather slack)

  u16* qkvT  = wsT;                  // [2][1152][384]
  u16* projT = qkvT + 2 * 442368;    // [2][384][384]
  u16* fc1T  = projT + 2 * 147456;   // [2][1536][384]
  u16* fc2T  = fc1T + 2 * 589824;    // [2][384][1536]
  u16* expT  = fc2T + 2 * 589824;    // [768][384]

  u16* p_n1g  = wsP + 0;      // 768
  u16* p_n1b  = wsP + 768;    // 768
  u16* p_qkvb = wsP + 1536;   // 2304
  u16* p_rpb  = wsP + 3840;   // 4056
  u16* p_prjb = wsP + 7896;   // 768
  u16* p_n2g  = wsP + 8664;   // 768
  u16* p_n2b  = wsP + 9432;   // 768
  u16* p_fc1b = wsP + 10200;  // 3072
  u16* p_fc2b = wsP + 13272;  // 768
  u16* p_exg  = wsP + 14040;  // 192
  u16* p_exb  = wsP + 14232;  // 192

  // 1) dtype detection from x's bit patterns
  detect_kernel<<<1, 256, 0, stream>>>((const u32*)d_in[0], flag);

  // 2) convert x and small params to canonical bf16 (vectorized x4)
  convert_kernel<<<(19267584 / 4 + 255) / 256, 256, 0, stream>>>(d_in[0], wsS, 19267584 / 4, flag);
  auto cv = [&](const void* src, u16* dst, int n) {
    convert_kernel<<<(n / 4 + 255) / 256, 256, 0, stream>>>(src, dst, n / 4, flag);
  };
  cv(d_in[1],  p_n1g, 768);   cv(d_in[2],  p_n1b, 768);
  cv(d_in[4],  p_qkvb, 2304); cv(d_in[5],  p_rpb, 4056);
  cv(d_in[7],  p_prjb, 768);  cv(d_in[8],  p_n2g, 768);
  cv(d_in[9],  p_n2b, 768);   cv(d_in[11], p_fc1b, 3072);
  cv(d_in[13], p_fc2b, 768);  cv(d_in[15], p_exg, 192);
  cv(d_in[16], p_exb, 192);

  // 3) weight transposes (+convert)
  {
    int tot;
    tot = 2 * 384 * 1152; transpose_kernel<<<(tot + 255) / 256, 256, 0, stream>>>(d_in[3],  qkvT, 384, 1152, tot, flag);
    tot = 2 * 384 * 384;  transpose_kernel<<<(tot + 255) / 256, 256, 0, stream>>>(d_in[6],  projT, 384, 384,  tot, flag);
    tot = 2 * 384 * 1536; transpose_kernel<<<(tot + 255) / 256, 256, 0, stream>>>(d_in[10], fc1T, 384, 1536, tot, flag);
    tot = 2 * 1536 * 384; transpose_kernel<<<(tot + 255) / 256, 256, 0, stream>>>(d_in[12], fc2T, 1536, 384, tot, flag);
    tot = 384 * 768;      transpose_kernel<<<(tot + 255) / 256, 256, 0, stream>>>(d_in[14], expT, 384, 768,  tot, flag);
  }

  // 4) two Swin blocks; residual stream lives in wsS (in-place updates)
  for (int i = 0; i < 2; ++i) {
    int shifted = i;
    // bias+mask table for this block (depends on rpb[i] and shifted)
    biastab_kernel<<<451, 256, 0, stream>>>(p_rpb + i * 2028, bt, shifted);
    // LN1 -> wsB
    ln384_kernel<<<12544, 256, 0, stream>>>(wsS, p_n1g + i * 384, p_n1b + i * 384, wsB);
    // QKV gemm (gathered windows) -> wsA (q/k/v scattered per head); grid 392*9 = 3528
    gemm_kernel<0><<<3528, 256, 0, stream>>>(wsB, qkvT + i * 442368, p_qkvb + i * 1152,
                                             nullptr, wsA, 1152, 384, shifted, 9);
    // attention (MFMA) -> wsB  ([w*49+n][head*32+hd])
    attn_mfma_kernel<<<3072, 256, 0, stream>>>(wsA, bt, wsB);
    // proj + residual + window-reverse scatter -> wsS (in-place); grid 392*3 = 1176
    gemm_kernel<1><<<1176, 256, 0, stream>>>(wsB, projT + i * 147456, p_prjb + i * 384,
                                             wsS, wsS, 384, 384, shifted, 3);
    // LN2 -> wsB
    ln384_kernel<<<12544, 256, 0, stream>>>(wsS, p_n2g + i * 384, p_n2b + i * 384, wsB);
    // FC1 + gelu -> wsA; grid 392*12 = 4704
    gemm_kernel<2><<<4704, 256, 0, stream>>>(wsB, fc1T + i * 589824, p_fc1b + i * 1536,
                                             nullptr, wsA, 1536, 384, 0, 12);
    // FC2 + residual -> wsS (in-place); grid 392*3 = 1176
    gemm_kernel<3><<<1176, 256, 0, stream>>>(wsA, fc2T + i * 589824, p_fc2b + i * 384,
                                             wsS, wsS, 384, 1536, 0, 3);
  }

  // 5) PatchExpand gemm -> wsA [50176][768]; grid 392*6 = 2352
  gemm_kernel<4><<<2352, 256, 0, stream>>>(wsS, expT, nullptr, nullptr, wsA, 768, 384, 0, 6);
  // 6) pixel-shuffle gather + LN(192) -> d_out (bf16 or fp32 per flag)
  lnfinal_kernel<<<25088, 256, 0, stream>>>(wsA, p_exg, p_exb, d_out, flag);
}

// Round 6
// 1057.923 us; speedup vs baseline: 1.0974x; 1.0186x over previous
//
#include <hip/hip_runtime.h>
#include <cstdint>
#include <cstddef>

typedef unsigned short u16;
typedef unsigned int u32;
typedef __attribute__((ext_vector_type(8))) short bf16x8;
typedef __attribute__((ext_vector_type(4))) float f32x4;

// ---------- bf16 helpers (raw-bit; software RNE — compiler-scheduled, known-good) ----------
__device__ __forceinline__ float bf2f(u32 u) {
  union { u32 i; float f; } c; c.i = u << 16; return c.f;
}
__device__ __forceinline__ u16 f2bf(float f) {
  union { float f; u32 i; } c; c.f = f;
  u32 r = c.i + 0x7fffu + ((c.i >> 16) & 1u);  // RNE
  return (u16)(r >> 16);
}

// GELU via Abramowitz-Stegun 7.1.25 3-term erf approx (|err| <= 2.5e-5, far below bf16 LSB).
__device__ __forceinline__ float gelu_f(float x) {
  float z = 0.70710678118654752f * x;
  float az = fabsf(z);
  float t = __builtin_amdgcn_rcpf(__builtin_fmaf(0.47047f, az, 1.f));
  float p = t * (0.3480242f + t * (-0.0958798f + t * 0.7478556f));
  float e = __expf(-az * az);
  float er = __builtin_fmaf(-p, e, 1.f);   // erf(|z|)
  er = copysignf(er, z);
  return 0.5f * x * (1.f + er);
}

// window-token row m (0..50175) -> source token row in (B,L) layout, with optional shift roll
__device__ __forceinline__ int srcrow_map(int m, int shifted) {
  int w = m / 49, n = m - w * 49;
  int b = w >> 6, wi = w & 63;
  int wy = wi >> 3, wx = wi & 7;
  int ty = n / 7, tx = n - ty * 7;
  int h = wy * 7 + ty, x = wx * 7 + tx;
  if (shifted) { h += 3; if (h >= 56) h -= 56; x += 3; if (x >= 56) x -= 56; }
  return b * 3136 + h * 56 + x;
}

// ---------------- dtype detection: are inputs packed bf16 or fp32? ----------------
__global__ void detect_kernel(const u32* __restrict__ x, int* __restrict__ flag) {
  int t = threadIdx.x;
  int c = 0;
  for (int i = t; i < 1024; i += 256) {
    u32 e = (x[i] >> 7) & 0xFFu;
    c += (e >= 100 && e <= 130) ? 1 : 0;
  }
#pragma unroll
  for (int m = 1; m < 64; m <<= 1) c += __shfl_xor(c, m, 64);
  __shared__ int part[4];
  if ((t & 63) == 0) part[t >> 6] = c;
  __syncthreads();
  if (t == 0) flag[0] = (part[0] + part[1] + part[2] + part[3] > 700) ? 1 : 0;
}

// ---------------- convert any input tensor to canonical bf16 (4 elems/thread) ----------------
__global__ void convert_kernel(const void* __restrict__ in, u16* __restrict__ out,
                               int n4, const int* __restrict__ flag) {
  int i = blockIdx.x * 256 + threadIdx.x;
  if (i >= n4) return;
  if (flag[0]) {
    ((uint2*)out)[i] = ((const uint2*)in)[i];
  } else {
    float4 v = ((const float4*)in)[i];
    uint2 r;
    r.x = (u32)f2bf(v.x) | ((u32)f2bf(v.y) << 16);
    r.y = (u32)f2bf(v.z) | ((u32)f2bf(v.w) << 16);
    ((uint2*)out)[i] = r;
  }
}

// ---------------- weight transpose (+convert): out[b][c][r] = in[b][r][c] ----------------
__global__ void transpose_kernel(const void* __restrict__ in, u16* __restrict__ out,
                                 int R, int C, int total, const int* __restrict__ flag) {
  int i = blockIdx.x * 256 + threadIdx.x;
  if (i >= total) return;
  int rc = R * C;
  int bb = i / rc, rem = i - bb * rc;
  int c = rem / R, r = rem - c * R;
  size_t s = (size_t)bb * rc + (size_t)r * C + c;
  out[i] = flag[0] ? ((const u16*)in)[s] : f2bf(((const float*)in)[s]);
}

// ---------------- LayerNorm over 384, one wave per row (bf16 in/out) ----------------
__global__ __launch_bounds__(256)
void ln384_kernel(const u16* __restrict__ in, const u16* __restrict__ g,
                  const u16* __restrict__ b, u16* __restrict__ out) {
  int row = blockIdx.x * 4 + (threadIdx.x >> 6);
  int lane = threadIdx.x & 63;
  const u32* p = (const u32*)(in + (size_t)row * 384);
  float x[6]; float sum = 0.f, sq = 0.f;
#pragma unroll
  for (int j = 0; j < 3; ++j) {
    u32 u = p[lane + 64 * j];
    float a0 = bf2f(u & 0xffff), a1 = bf2f(u >> 16);
    x[2 * j] = a0; x[2 * j + 1] = a1;
    sum += a0 + a1; sq += a0 * a0 + a1 * a1;
  }
#pragma unroll
  for (int m = 1; m < 64; m <<= 1) { sum += __shfl_xor(sum, m, 64); sq += __shfl_xor(sq, m, 64); }
  float mean = sum * (1.f / 384.f);
  float var = sq * (1.f / 384.f) - mean * mean;
  float rstd = rsqrtf(var + 1e-5f);
  u32* op = (u32*)(out + (size_t)row * 384);
  const u32* g32 = (const u32*)g; const u32* b32 = (const u32*)b;
#pragma unroll
  for (int j = 0; j < 3; ++j) {
    int c = lane + 64 * j;
    u32 gg = g32[c], bb = b32[c];
    float y0 = (x[2 * j] - mean) * rstd * bf2f(gg & 0xffff) + bf2f(bb & 0xffff);
    float y1 = (x[2 * j + 1] - mean) * rstd * bf2f(gg >> 16) + bf2f(bb >> 16);
    op[c] = (u32)f2bf(y0) | ((u32)f2bf(y1) << 16);
  }
}

// ---------------- final LN over 192 with pixel-shuffle gather; flag-typed store ----------------
__global__ __launch_bounds__(256)
void lnfinal_kernel(const u16* __restrict__ in, const u16* __restrict__ g,
                    const u16* __restrict__ b, void* __restrict__ outv,
                    const int* __restrict__ flag) {
  int row = blockIdx.x * 8 + (threadIdx.x >> 5);  // rows = 16*12544 = 200704
  int s = threadIdx.x & 31;
  int fl = flag[0];
  int bb = row / 12544, rem = row - bb * 12544;
  int hh = rem / 112, wp = rem - hh * 112;
  int h = hh >> 1, a = hh & 1, w = wp >> 1, c2 = wp & 1;
  const u32* p = (const u32*)(in + ((size_t)(bb * 3136 + h * 56 + w)) * 768 + (a * 2 + c2) * 192);
  float x[6]; float sum = 0.f, sq = 0.f;
#pragma unroll
  for (int j = 0; j < 3; ++j) {
    u32 u = p[s + 32 * j];
    float a0 = bf2f(u & 0xffff), a1 = bf2f(u >> 16);
    x[2 * j] = a0; x[2 * j + 1] = a1;
    sum += a0 + a1; sq += a0 * a0 + a1 * a1;
  }
#pragma unroll
  for (int m = 1; m < 32; m <<= 1) { sum += __shfl_xor(sum, m, 32); sq += __shfl_xor(sq, m, 32); }
  float mean = sum * (1.f / 192.f);
  float var = sq * (1.f / 192.f) - mean * mean;
  float rstd = rsqrtf(var + 1e-5f);
  const u32* g32 = (const u32*)g; const u32* b32 = (const u32*)b;
#pragma unroll
  for (int j = 0; j < 3; ++j) {
    int c = s + 32 * j;
    u32 gg = g32[c], bv = b32[c];
    float y0 = (x[2 * j] - mean) * rstd * bf2f(gg & 0xffff) + bf2f(bv & 0xffff);
    float y1 = (x[2 * j + 1] - mean) * rstd * bf2f(gg >> 16) + bf2f(bv >> 16);
    if (fl) {
      u32* op = (u32*)((u16*)outv + (size_t)row * 192);
      op[c] = (u32)f2bf(y0) | ((u32)f2bf(y1) << 16);
    } else {
      float2* op = (float2*)((float*)outv + (size_t)row * 192);
      float2 v; v.x = y0; v.y = y1;
      op[c] = v;
    }
  }
}

// ---------------- MFMA GEMM: C[M,N] = A[M,K] @ Bt[N,K]^T (+epilogue) ----------------
// T1 XCD-chunked swizzle; 2-deep LDS double-buffer (32KB -> 5 blocks/CU by LDS) with
// stage-before-compute. R5 lesson: 48KB 3-ring cost a resident block (occ 38.9->28) and
// barely beat the drain -- TLP across blocks hides both load latency AND the VALU-heavy
// epilogue (m114 overlap), so occupancy > pipeline depth here.
// Epilogue: row-major store order (ideal WRITE_SIZE, R5-verified), hoisted rowoff /
// per-nt tables, 3-term A-S GELU.
// MODE 0: QKV   A gathered via window map; +bias; q*=1/sqrt(32); scatter [part][w][head][n][hd]
// MODE 1: PROJ  +bias +resid[src]; scatter rows via window map -> C[src] (in-place with resid)
// MODE 2: FC1   +bias; GELU; C row-major stride N
// MODE 3: FC2   +bias +resid[row]; C[row] (in-place with resid)
// MODE 4: EXPAND no bias; C row-major stride N
template <int MODE>
__global__ __launch_bounds__(256, 4)
void gemm_kernel(const u16* __restrict__ A, const u16* __restrict__ Bt,
                 const u16* __restrict__ bias, const u16* __restrict__ resid,
                 u16* __restrict__ C, int N, int K, int shifted, int nn) {
  __shared__ __attribute__((aligned(16))) char smem[32768];  // 2 x { A[128][32], B[128][32] } bf16

  const int t = threadIdx.x;
  const int lane = t & 63;
  const int wave = t >> 6;

  // T1: XCD-aware swizzle (gridDim.x % 8 == 0 for all launches -> bijective chunked map)
  const int wgid = (blockIdx.x & 7) * ((int)gridDim.x >> 3) + (blockIdx.x >> 3);
  const int mblk = wgid / nn, nblk = wgid - mblk * nn;

  // staging: 512 chunks of 16B per tile; thread t stages chunks t and t+256 (4 loads/thread)
  const u16* aptr[2]; const u16* bptr[2];
  char* ldsa[2]; char* ldsb[2];
#pragma unroll
  for (int i = 0; i < 2; ++i) {
    int c = t + i * 256;
    int r = c >> 2, off8 = (c & 3) * 8;
    int gr = mblk * 128 + r;
    int src = (MODE == 0) ? srcrow_map(gr, shifted) : gr;
    aptr[i] = A + (size_t)src * K + off8;
    int gn = nblk * 128 + r;
    bptr[i] = Bt + (size_t)gn * K + off8;
    ldsa[i] = smem + c * 16;
    ldsb[i] = smem + 8192 + c * 16;
  }

  f32x4 acc[4][4];
#pragma unroll
  for (int i = 0; i < 4; ++i)
#pragma unroll
    for (int j = 0; j < 4; ++j) { f32x4 z = {0.f, 0.f, 0.f, 0.f}; acc[i][j] = z; }

  const int quad = lane >> 4, l15 = lane & 15;
  const int wm = (wave >> 1) * 64, wn = (wave & 1) * 64;

  auto stage = [&](int b) {
#pragma unroll
    for (int i = 0; i < 2; ++i) {
      __builtin_amdgcn_global_load_lds((const void*)aptr[i], (void*)(ldsa[i] + b * 16384), 16, 0, 0);
      __builtin_amdgcn_global_load_lds((const void*)bptr[i], (void*)(ldsb[i] + b * 16384), 16, 0, 0);
      aptr[i] += 32; bptr[i] += 32;
    }
  };
  auto compute = [&](int b) {
    const u16* As = (const u16*)(smem + b * 16384);
    const u16* Bs = (const u16*)(smem + b * 16384 + 8192);
    bf16x8 af[4], bfv[4];
#pragma unroll
    for (int mt = 0; mt < 4; ++mt)
      af[mt] = *(const bf16x8*)(As + (wm + mt * 16 + l15) * 32 + quad * 8);
#pragma unroll
    for (int nt = 0; nt < 4; ++nt)
      bfv[nt] = *(const bf16x8*)(Bs + (wn + nt * 16 + l15) * 32 + quad * 8);
#pragma unroll
    for (int mt = 0; mt < 4; ++mt)
#pragma unroll
      for (int nt = 0; nt < 4; ++nt)
        acc[mt][nt] = __builtin_amdgcn_mfma_f32_16x16x32_bf16(af[mt], bfv[nt], acc[mt][nt], 0, 0, 0);
  };

  // 2-phase: prologue stage, then {stage(next); compute(cur); barrier}
  const int ktiles = K >> 5;
  stage(0);
  __syncthreads();
  int cur = 0;
  for (int kt = 0; kt < ktiles - 1; ++kt) {
    stage(cur ^ 1);   // next-tile loads in flight under compute(cur) + other blocks' work
    compute(cur);
    __syncthreads();  // drains next tile; 4-5 resident blocks cover the stall
    cur ^= 1;
  }
  compute(cur);

  // ---- epilogue ----
  // per-(mt,r) row offsets (divisions hoisted)
  size_t rowoff[4][4];
#pragma unroll
  for (int mt = 0; mt < 4; ++mt) {
#pragma unroll
    for (int r = 0; r < 4; ++r) {
      int rr = mblk * 128 + wm + mt * 16 + quad * 4 + r;
      if (MODE == 0) {
        int w49 = rr / 49, n49 = rr - w49 * 49;
        rowoff[mt][r] = (size_t)(w49 * 18816 + n49 * 32);   // w49*12*49*32 + n49*32
      } else if (MODE == 1) {
        rowoff[mt][r] = (size_t)srcrow_map(rr, shifted) * 384;
      } else {
        rowoff[mt][r] = (size_t)rr * (size_t)N;
      }
    }
  }
  // per-nt column constants
  size_t ntoff[4]; float bcolv[4]; float qscv[4];
#pragma unroll
  for (int nt = 0; nt < 4; ++nt) {
    const int cb = nblk * 128 + wn + nt * 16;   // lane-uniform col base (mult of 16)
    const int col = cb + l15;
    bcolv[nt] = (MODE == 4) ? 0.f : bf2f(bias[col]);
    qscv[nt] = 1.f;
    if (MODE == 0) {
      int part = cb / 384;
      int cw = cb - part * 384;
      int head = cw >> 5, hdb = cw & 31;
      qscv[nt] = (part == 0) ? 0.17677669529663689f : 1.f;  // HD^-0.5 on q
      ntoff[nt] = (size_t)part * 19267584 + (size_t)head * 1568 + (size_t)(hdb + l15);
    } else {
      ntoff[nt] = (size_t)col;
    }
  }
  // row-major store order: for a fixed output row, the wave's 4 nt chunks are written
  // back-to-back -> full-line HBM writes (R5-measured ideal WRITE_SIZE)
#pragma unroll
  for (int mt = 0; mt < 4; ++mt) {
#pragma unroll
    for (int r = 0; r < 4; ++r) {
      const size_t ro = rowoff[mt][r];
#pragma unroll
      for (int nt = 0; nt < 4; ++nt) {
        float v = acc[mt][nt][r];
        size_t o = ro + ntoff[nt];
        if (MODE == 0) {
          C[o] = f2bf((v + bcolv[nt]) * qscv[nt]);
        } else if (MODE == 1) {
          C[o] = f2bf(v + bcolv[nt] + bf2f(resid[o]));
        } else if (MODE == 2) {
          C[o] = f2bf(gelu_f(v + bcolv[nt]));
        } else if (MODE == 3) {
          C[o] = f2bf(v + bcolv[nt] + bf2f(resid[o]));
        } else {
          C[o] = f2bf(v);
        }
      }
    }
  }
}

// ---------------- bias+mask table precompute: bt[cls][head][i][j] f32 ----------------
// cls = (wy==7)*2 + (wx==7): window edge class. Mask (-100) folded in when shifted.
__global__ void biastab_kernel(const u16* __restrict__ rpb, float* __restrict__ bt, int shifted) {
  int idx = blockIdx.x * 256 + threadIdx.x;
  if (idx >= 4 * 12 * 2401) return;
  int ij = idx % 2401, ch = idx / 2401;
  int head = ch % 12, cls = ch / 12;
  int i = ij / 49, j = ij % 49;
  int iy = i / 7, ix = i - iy * 7, jy = j / 7, jx = j - jy * 7;
  int rp = (iy - jy + 6) * 13 + (ix - jx + 6);
  float v = bf2f(rpb[rp * 12 + head]);
  if (shifted) {
    int clsy = cls >> 1, clsx = cls & 1;
    int regi = (clsy ? (iy < 4 ? 1 : 2) : 0) * 3 + (clsx ? (ix < 4 ? 1 : 2) : 0);
    int regj = (clsy ? (jy < 4 ? 1 : 2) : 0) * 3 + (clsx ? (jx < 4 ? 1 : 2) : 0);
    if (regi != regj) v -= 100.f;
  }
  bt[idx] = v;
}

// ---------------- MFMA attention: one wave per (window, head) ----------------
// qkv layout: [part 0..2][w 0..1023][head 0..11][n 0..48][hd 0..31] bf16; N padded 49->64.
// QK^T: 16 mfma_16x16x32; softmax in-register (16-lane shfl reductions);
// P -> XOR-swizzled LDS (8KB/wave) as bf16; PV: 16 mfma with V fragments gathered to regs.
__global__ __launch_bounds__(256, 3)
void attn_mfma_kernel(const u16* __restrict__ qkv, const float* __restrict__ bt,
                      u16* __restrict__ o) {
  __shared__ __attribute__((aligned(16))) char pbuf[4][8192];
  const int wave = threadIdx.x >> 6;
  const int lane = threadIdx.x & 63;
  const int quad = lane >> 4, l15 = lane & 15;
  const int blk = blockIdx.x * 4 + wave;
  const int w = blk / 12, head = blk - w * 12;
  const int wi = w & 63;
  const int cls = (((wi >> 3) == 7) ? 2 : 0) + (((wi & 7) == 7) ? 1 : 0);
  const float* btw = bt + (size_t)(cls * 12 + head) * 2401;
  char* pw = &pbuf[wave][0];

  const size_t base = (size_t)blk * 1568;
  const u16* qp = qkv + base;
  const u16* kp = qkv + 19267584 + base;
  const u16* vp = qkv + 2 * 19267584 + base;

  // Q/K fragments: row/col = tile*16 + l15, k = quad*8 + 0..7  (16B contiguous loads)
  bf16x8 qf[4], kf[4];
#pragma unroll
  for (int mi = 0; mi < 4; ++mi)
    qf[mi] = *(const bf16x8*)(qp + (size_t)(mi * 16 + l15) * 32 + quad * 8);
#pragma unroll
  for (int nj = 0; nj < 4; ++nj)
    kf[nj] = *(const bf16x8*)(kp + (size_t)(nj * 16 + l15) * 32 + quad * 8);

  // V fragments (B-operand for PV): vf[kk][n2][j] = V[kk*32+quad*8+j][n2*16+l15]
  // keys >= 49 zeroed in-register (last block over-reads uninitialized ws -> must not enter MFMA)
  bf16x8 vf[2][2];
#pragma unroll
  for (int kk = 0; kk < 2; ++kk)
#pragma unroll
    for (int n2 = 0; n2 < 2; ++n2) {
      bf16x8 tv;
#pragma unroll
      for (int j = 0; j < 8; ++j) {
        int key = kk * 32 + quad * 8 + j;
        u16 raw = vp[(size_t)key * 32 + n2 * 16 + l15];
        tv[j] = (key < 49) ? (short)raw : (short)0;
      }
      vf[kk][n2] = tv;
    }

  // S = Q K^T  (64x64 padded)
  f32x4 s[4][4];
#pragma unroll
  for (int mi = 0; mi < 4; ++mi)
#pragma unroll
    for (int nj = 0; nj < 4; ++nj) { f32x4 z = {0.f, 0.f, 0.f, 0.f}; s[mi][nj] = z; }
#pragma unroll
  for (int mi = 0; mi < 4; ++mi)
#pragma unroll
    for (int nj = 0; nj < 4; ++nj)
      s[mi][nj] = __builtin_amdgcn_mfma_f32_16x16x32_bf16(qf[mi], kf[nj], s[mi][nj], 0, 0, 0);

  // bias + mask + softmax per row; write normalized bf16 P to swizzled LDS
  const bool c3ok = (l15 == 0);  // col 48 is the only valid col in nj=3 tile
#pragma unroll
  for (int mi = 0; mi < 4; ++mi) {
#pragma unroll
    for (int r = 0; r < 4; ++r) {
      int i = mi * 16 + quad * 4 + r;  // C-layout row
      const float* brow = btw + i * 49;
      float v0 = s[mi][0][r] + brow[l15];
      float v1 = s[mi][1][r] + brow[l15 + 16];
      float v2 = s[mi][2][r] + brow[l15 + 32];
      float v3 = c3ok ? (s[mi][3][r] + brow[48]) : -1e30f;  // replace (kills NaN), not add
      float mx = fmaxf(fmaxf(v0, v1), fmaxf(v2, v3));
#pragma unroll
      for (int t = 1; t < 16; t <<= 1) mx = fmaxf(mx, __shfl_xor(mx, t, 64));
      float e0 = __expf(v0 - mx), e1 = __expf(v1 - mx);
      float e2 = __expf(v2 - mx), e3 = __expf(v3 - mx);
      float ls = e0 + e1 + e2 + e3;
#pragma unroll
      for (int t = 1; t < 16; t <<= 1) ls += __shfl_xor(ls, t, 64);
      float inv = 1.f / ls;
      u32 sw = (u32)((i & 7) << 4);  // G4 XOR swizzle: row stride 128B would be 32-way conflict
      *(u16*)(pw + (((u32)(i * 128 + l15 * 2)) ^ sw)) = f2bf(e0 * inv);
      *(u16*)(pw + (((u32)(i * 128 + (l15 + 16) * 2)) ^ sw)) = f2bf(e1 * inv);
      *(u16*)(pw + (((u32)(i * 128 + (l15 + 32) * 2)) ^ sw)) = f2bf(e2 * inv);
      *(u16*)(pw + (((u32)(i * 128 + (l15 + 48) * 2)) ^ sw)) = f2bf(e3 * inv);
    }
  }

  // drain P writes before A-fragment reads (same wave, private LDS region)
  asm volatile("s_waitcnt lgkmcnt(0)" ::: "memory");
  __builtin_amdgcn_sched_barrier(0);

  // O = P V
  f32x4 oacc[4][2];
#pragma unroll
  for (int mi = 0; mi < 4; ++mi)
#pragma unroll
    for (int n2 = 0; n2 < 2; ++n2) { f32x4 z = {0.f, 0.f, 0.f, 0.f}; oacc[mi][n2] = z; }
#pragma unroll
  for (int mi = 0; mi < 4; ++mi) {
#pragma unroll
    for (int kk = 0; kk < 2; ++kk) {
      int arow = mi * 16 + l15;
      u32 ab = ((u32)(arow * 128 + (kk * 32 + quad * 8) * 2)) ^ ((u32)((arow & 7) << 4));
      bf16x8 pf = *(const bf16x8*)(pw + ab);
#pragma unroll
      for (int n2 = 0; n2 < 2; ++n2)
        oacc[mi][n2] = __builtin_amdgcn_mfma_f32_16x16x32_bf16(pf, vf[kk][n2], oacc[mi][n2], 0, 0, 0);
    }
  }

  // store valid rows (row < 49): o[(w*49+row)*384 + head*32 + hd]
#pragma unroll
  for (int mi = 0; mi < 4; ++mi)
#pragma unroll
    for (int r = 0; r < 4; ++r) {
      int row = mi * 16 + quad * 4 + r;
      if (row < 49) {
        u16* orow = o + ((size_t)(w * 49 + row)) * 384 + head * 32;
        orow[l15] = f2bf(oacc[mi][0][r]);
        orow[16 + l15] = f2bf(oacc[mi][1][r]);
      }
    }
}

// ---------------- host orchestration ----------------
extern "C" void kernel_launch(void* const* d_in, const int* in_sizes, int n_in,
                              void* d_out, int out_size, void* d_ws, size_t ws_size,
                              hipStream_t stream) {
  char* ws = (char*)d_ws;
  u16* wsA  = (u16*)ws;                          // 154,140,672 B: QKV / FC1-act / expand-out
  u16* wsS  = (u16*)(ws + 154140672);            // 38,535,168 B: converted x -> residual stream (in-place)
  u16* wsB  = (u16*)(ws + 192675840);            // 38,535,168 B: LN out / attn out
  u16* wsT  = (u16*)(ws + 231211008);            // 7,667,712 B: transposed weights
  u16* wsP  = (u16*)(ws + 238878720);            // 28,848 B: converted params
  int* flag = (int*)(ws + 238907568);            // 4 B
  // bias table parked in wsA tail: QKV occupies first 115,605,504 B (+ <1KB over-read slack);
  // FC1 later overwrites it, so it is rebuilt every block-iteration before attention.
  float* bt = (float*)(ws + 115736576);          // 4*12*2401 f32 (+ gather slack)

  u16* qkvT  = wsT;                  // [2][1152][384]
  u16* projT = qkvT + 2 * 442368;    // [2][384][384]
  u16* fc1T  = projT + 2 * 147456;   // [2][1536][384]
  u16* fc2T  = fc1T + 2 * 589824;    // [2][384][1536]
  u16* expT  = fc2T + 2 * 589824;    // [768][384]

  u16* p_n1g  = wsP + 0;      // 768
  u16* p_n1b  = wsP + 768;    // 768
  u16* p_qkvb = wsP + 1536;   // 2304
  u16* p_rpb  = wsP + 3840;   // 4056
  u16* p_prjb = wsP + 7896;   // 768
  u16* p_n2g  = wsP + 8664;   // 768
  u16* p_n2b  = wsP + 9432;   // 768
  u16* p_fc1b = wsP + 10200;  // 3072
  u16* p_fc2b = wsP + 13272;  // 768
  u16* p_exg  = wsP + 14040;  // 192
  u16* p_exb  = wsP + 14232;  // 192

  // 1) dtype detection from x's bit patterns
  detect_kernel<<<1, 256, 0, stream>>>((const u32*)d_in[0], flag);

  // 2) convert x and small params to canonical bf16 (vectorized x4)
  convert_kernel<<<(19267584 / 4 + 255) / 256, 256, 0, stream>>>(d_in[0], wsS, 19267584 / 4, flag);
  auto cv = [&](const void* src, u16* dst, int n) {
    convert_kernel<<<(n / 4 + 255) / 256, 256, 0, stream>>>(src, dst, n / 4, flag);
  };
  cv(d_in[1],  p_n1g, 768);   cv(d_in[2],  p_n1b, 768);
  cv(d_in[4],  p_qkvb, 2304); cv(d_in[5],  p_rpb, 4056);
  cv(d_in[7],  p_prjb, 768);  cv(d_in[8],  p_n2g, 768);
  cv(d_in[9],  p_n2b, 768);   cv(d_in[11], p_fc1b, 3072);
  cv(d_in[13], p_fc2b, 768);  cv(d_in[15], p_exg, 192);
  cv(d_in[16], p_exb, 192);

  // 3) weight transposes (+convert)
  {
    int tot;
    tot = 2 * 384 * 1152; transpose_kernel<<<(tot + 255) / 256, 256, 0, stream>>>(d_in[3],  qkvT, 384, 1152, tot, flag);
    tot = 2 * 384 * 384;  transpose_kernel<<<(tot + 255) / 256, 256, 0, stream>>>(d_in[6],  projT, 384, 384,  tot, flag);
    tot = 2 * 384 * 1536; transpose_kernel<<<(tot + 255) / 256, 256, 0, stream>>>(d_in[10], fc1T, 384, 1536, tot, flag);
    tot = 2 * 1536 * 384; transpose_kernel<<<(tot + 255) / 256, 256, 0, stream>>>(d_in[12], fc2T, 1536, 384, tot, flag);
    tot = 384 * 768;      transpose_kernel<<<(tot + 255) / 256, 256, 0, stream>>>(d_in[14], expT, 384, 768,  tot, flag);
  }

  // 4) two Swin blocks; residual stream lives in wsS (in-place updates)
  for (int i = 0; i < 2; ++i) {
    int shifted = i;
    // bias+mask table for this block (depends on rpb[i] and shifted)
    biastab_kernel<<<451, 256, 0, stream>>>(p_rpb + i * 2028, bt, shifted);
    // LN1 -> wsB
    ln384_kernel<<<12544, 256, 0, stream>>>(wsS, p_n1g + i * 384, p_n1b + i * 384, wsB);
    // QKV gemm (gathered windows) -> wsA (q/k/v scattered per head); grid 392*9 = 3528
    gemm_kernel<0><<<3528, 256, 0, stream>>>(wsB, qkvT + i * 442368, p_qkvb + i * 1152,
                                             nullptr, wsA, 1152, 384, shifted, 9);
    // attention (MFMA) -> wsB  ([w*49+n][head*32+hd])
    attn_mfma_kernel<<<3072, 256, 0, stream>>>(wsA, bt, wsB);
    // proj + residual + window-reverse scatter -> wsS (in-place); grid 392*3 = 1176
    gemm_kernel<1><<<1176, 256, 0, stream>>>(wsB, projT + i * 147456, p_prjb + i * 384,
                                             wsS, wsS, 384, 384, shifted, 3);
    // LN2 -> wsB
    ln384_kernel<<<12544, 256, 0, stream>>>(wsS, p_n2g + i * 384, p_n2b + i * 384, wsB);
    // FC1 + gelu -> wsA; grid 392*12 = 4704
    gemm_kernel<2><<<4704, 256, 0, stream>>>(wsB, fc1T + i * 589824, p_fc1b + i * 1536,
                                             nullptr, wsA, 1536, 384, 0, 12);
    // FC2 + residual -> wsS (in-place); grid 392*3 = 1176
    gemm_kernel<3><<<1176, 256, 0, stream>>>(wsA, fc2T + i * 589824, p_fc2b + i * 384,
                                             wsS, wsS, 384, 1536, 0, 3);
  }

  // 5) PatchExpand gemm -> wsA [50176][768]; grid 392*6 = 2352
  gemm_kernel<4><<<2352, 256, 0, stream>>>(wsS, expT, nullptr, nullptr, wsA, 768, 384, 0, 6);
  // 6) pixel-shuffle gather + LN(192) -> d_out (bf16 or fp32 per flag)
  lnfinal_kernel<<<25088, 256, 0, stream>>>(wsA, p_exg, p_exb, d_out, flag);
}